// Round 1
// baseline (278.554 us; speedup 1.0000x reference)
//
#include <hip/hip_runtime.h>

#define G_CONST     9.81f
#define DT_VEL_     0.01f
#define MAX_THRUST_ 39.96f                 // 0.9 * 44.4
#define MAX_ANGLE_  0.5235987755982988f    // 30 deg in rad
#define ALPHA_      0.16666667f            // DT/(TAU+DT) in f32
#define TPB         256
#define DPT         4                      // drones per thread
#define DPB         (TPB * DPT)            // 1024 drones per block

__device__ __forceinline__ void pid_one(
    const float* rv, const float* mv, const float* pi,
    const float* pe, const float* pd,
    float yaw, float m,
    float& rp0o, float& rp1o, float& th)
{
    const float KP[3] = {2.0f, 2.0f, 4.0f};
    const float KI[3] = {0.5f, 0.5f, 1.0f};
    const float KD[3] = {0.1f, 0.1f, 0.05f};
    float u[3];
#pragma unroll
    for (int c = 0; c < 3; ++c) {
        float err   = rv[c] - mv[c];
        float integ = pi[c] + err * DT_VEL_;
        float d_raw = (err - pe[c]) / DT_VEL_;
        float d     = pd[c] + ALPHA_ * (d_raw - pd[c]);
        float uu    = KP[c] * err + KI[c] * integ + KD[c] * d;
        u[c] = fminf(fmaxf(uu, -6.0f), 6.0f);
    }
    float s, c;
    __sincosf(yaw, &s, &c);
    float rp0 = (s * u[0] - c * u[1]) / G_CONST;
    float rp1 = (c * u[0] + s * u[1]) / G_CONST;
    float mag = sqrtf(rp0 * rp0 + rp1 * rp1);
    float sc  = fminf(MAX_ANGLE_ / (mag + 1e-6f), 1.0f);
    sc = (mag > MAX_ANGLE_) ? sc : 1.0f;
    rp0o = rp0 * sc;
    rp1o = rp1 * sc;
    th = fminf(fmaxf(m * G_CONST + m * u[2], 0.8f * G_CONST * m), MAX_THRUST_);
}

// Load 12 consecutive floats (4 drones x vec3) as 3 aligned float4s into
// a register array (all constant indices -> SROA keeps it in VGPRs).
__device__ __forceinline__ void load12(const float* __restrict__ p, float* d)
{
    const float4* p4 = (const float4*)p;
    float4 a = p4[0];
    float4 b = p4[1];
    float4 c = p4[2];
    d[0]  = a.x; d[1]  = a.y; d[2]  = a.z; d[3]  = a.w;
    d[4]  = b.x; d[5]  = b.y; d[6]  = b.z; d[7]  = b.w;
    d[8]  = c.x; d[9]  = c.y; d[10] = c.z; d[11] = c.w;
}

__global__ __launch_bounds__(TPB) void pos_ctrl_v4(
    const float* __restrict__ ref_ve,
    const float* __restrict__ meas_ve,
    const float* __restrict__ meas_yaw,
    const float* __restrict__ mass,
    const float* __restrict__ pid_int,
    const float* __restrict__ pid_prev_err,
    const float* __restrict__ pid_prev_d,
    float* __restrict__ out,   // fp32: [n*2 rp interleaved][n thrust]
    int n)
{
    const long t    = (long)blockIdx.x * TPB + threadIdx.x;  // global thread id
    const long base = t * DPT;                               // first drone of this thread

    if (base + DPT <= n) {
        // ---- loads: 17 independent 16B loads, all in flight before any use ----
        const size_t g = (size_t)base * 3;   // float offset; byte offset 48*t (16B-aligned)
        float rv[12], mv[12], pi[12], pe[12], pd[12];
        load12(ref_ve       + g, rv);
        load12(meas_ve      + g, mv);
        load12(pid_int      + g, pi);
        load12(pid_prev_err + g, pe);
        load12(pid_prev_d   + g, pd);
        const float4 yw4 = ((const float4*)meas_yaw)[t];
        const float4 m4  = ((const float4*)mass)[t];
        const float yw[4] = {yw4.x, yw4.y, yw4.z, yw4.w};
        const float mm[4] = {m4.x,  m4.y,  m4.z,  m4.w};

        // ---- compute 4 drones, fully unrolled ----
        float rp[8], thr[4];
#pragma unroll
        for (int d = 0; d < DPT; ++d) {
            pid_one(&rv[d * 3], &mv[d * 3], &pi[d * 3], &pe[d * 3], &pd[d * 3],
                    yw[d], mm[d], rp[d * 2], rp[d * 2 + 1], thr[d]);
        }

        // ---- stores: rp = 2x float4 (byte offset 32*t, aligned); thrust = 1x float4 ----
        float4* outrp = (float4*)(out + (size_t)base * 2);
        outrp[0] = make_float4(rp[0], rp[1], rp[2], rp[3]);
        outrp[1] = make_float4(rp[4], rp[5], rp[6], rp[7]);
        float* thrp = out + 2 * (size_t)n + base;
        if ((n & 3) == 0) {   // block-uniform; guarantees 16B alignment of thrust slab
            *(float4*)thrp = make_float4(thr[0], thr[1], thr[2], thr[3]);
        } else {
#pragma unroll
            for (int d = 0; d < DPT; ++d) thrp[d] = thr[d];
        }
    } else {
        // tail: per-drone scalar path (never taken for n % 1024 == 0)
#pragma unroll
        for (int d = 0; d < DPT; ++d) {
            const long i = base + d;
            if (i < n) {
                const size_t k = (size_t)i * 3;
                float rp0, rp1, th;
                pid_one(&ref_ve[k], &meas_ve[k], &pid_int[k], &pid_prev_err[k],
                        &pid_prev_d[k], meas_yaw[i], mass[i], rp0, rp1, th);
                out[(size_t)i * 2 + 0] = rp0;
                out[(size_t)i * 2 + 1] = rp1;
                out[2 * (size_t)n + i] = th;
            }
        }
    }
}

extern "C" void kernel_launch(void* const* d_in, const int* in_sizes, int n_in,
                              void* d_out, int out_size, void* d_ws, size_t ws_size,
                              hipStream_t stream) {
    const float* ref_ve       = (const float*)d_in[0];
    const float* meas_ve      = (const float*)d_in[1];
    const float* meas_yaw     = (const float*)d_in[2];
    const float* mass         = (const float*)d_in[3];
    const float* pid_int      = (const float*)d_in[4];
    const float* pid_prev_err = (const float*)d_in[5];
    const float* pid_prev_d   = (const float*)d_in[6];
    float* out = (float*)d_out;
    const int n = in_sizes[2];  // meas_yaw element count == N

    const int grid = (n + DPB - 1) / DPB;
    pos_ctrl_v4<<<grid, TPB, 0, stream>>>(
        ref_ve, meas_ve, meas_yaw, mass, pid_int, pid_prev_err, pid_prev_d, out, n);
}